// Round 4
// baseline (185.447 us; speedup 1.0000x reference)
//
#include <hip/hip_runtime.h>
#include <math.h>

// PCE basis expansion: Phi[n,b] = prod_j polyval(xn[n,j], idxset[b,j])
// D=50, P=2. Output 32768x1326 fp32 = 174 MB -> write-BW floor ~26 us.
//
// R5: dwordx4 stores via row-pairs. Evidence: R3 (scalar strided stores)
// +27 us, R4 (LDS conflict fix) +-0 -> pce is store-side limited, reads
// have slack. Rows 2m,2m+1 concatenated = 2652 floats = 663 float4s, and
// even-row bases are 16B-aligned (2*5304 % 16 == 0) -> every store is an
// aligned global_store_dwordx4 (1024 B/wave-instr, half the instr count).
// Row membership of each column folds into the descriptor: offset += RS
// selects the odd LDS row (adjacent in the flat table; 239 < 256 fits the
// 8-bit field). Varying factors now stride 4 across lanes -> would be an
// 8-way bank conflict; pad map p(k)=k+(k>>3) (baked into decode-time
// descriptors, zero runtime cost) restores ~2-way (free, m136). The ONLY
// effective change vs R4 is store width/count.
// Column -> factors closed form (verified R3/R4, absmax 0):
//   c==0 -> 1 ; 1<=c<=50 -> rev[c-1] ; c>=51: t=c-51, q=trinv(t), s=t-T(q);
//   s==q -> H2[q] else rev[s]*rev[q],  rev[k]=H1(x_{49-k}).

#define DD     50
#define NBASIS 1326
#define NF4    663            // float4s per row-pair (2*1326/4)
#define BN     16
#define NM     (BN / 2)       // 8 row-pairs per block
#define BLOCK  256
#define RS     120            // LDS row stride in floats
#define ONE    56             // slot holding 1.0 (in the p(k) gap, k<50 -> p<=55)
#define H2OFF  64             // padded H2 base; max off = 64+55 = 119 < RS

__device__ __forceinline__ int padk(int k) { return k + (k >> 3); }

// col -> (off0 | off1<<8), offsets into the padded per-row table
__device__ __forceinline__ int col_desc(int c) {
    if (c == 0) return ONE | (ONE << 8);
    if (c <= DD) return padk(c - 1) | (ONE << 8);      // rev[c-1] * 1.0
    int t = c - (DD + 1);                              // order-2 block index
    int q = (int)((sqrtf((float)(8 * t + 1)) - 1.0f) * 0.5f);
    while ((q + 1) * (q + 2) / 2 <= t) ++q;            // exact fix-up
    while (q * (q + 1) / 2 > t) --q;
    int s = t - q * (q + 1) / 2;                       // position within run q
    if (s == q) return (H2OFF + padk(q)) | (ONE << 8); // H2(x_{49-q}) * 1.0
    return padk(s) | (padk(q) << 8);                   // rev[s] * rev[q]
}

__global__ __launch_bounds__(BLOCK) void pce_kernel(
    const float* __restrict__ x, const float* __restrict__ mean,
    const float* __restrict__ var, const float* __restrict__ basis,
    float* __restrict__ out, int n)
{
    __shared__ float T[BN][RS];   // 16 x 120 floats = 7.5 KB, rows adjacent
    const int tid  = threadIdx.x;
    const int row0 = blockIdx.x * BN;

    // Hermite basis coefficients (broadcast loads, cached)
    float b10 = basis[3], b11 = basis[4], b12 = basis[5];
    float b20 = basis[6], b21 = basis[7], b22 = basis[8];

    // ---- Decode: 3 float4 slots x 4 columns, once per thread ----
    int dsc[3][4];                      // fully unrolled -> stays in VGPRs
    #pragma unroll
    for (int s = 0; s < 3; ++s) {
        int f  = tid + s * BLOCK;
        bool ok = (f < NF4);
        #pragma unroll
        for (int j = 0; j < 4; ++j) {
            int c2  = ok ? (4 * f + j) : 0;            // col in 2652-float pair
            int rf  = (c2 >= NBASIS) ? 1 : 0;          // 0: row 2m, 1: row 2m+1
            int col = c2 - rf * NBASIS;
            dsc[s][j] = col_desc(col) + rf * (RS + (RS << 8)); // bias both fields
        }
    }
    const bool has2 = (tid < NF4 - 2 * BLOCK);         // tid < 151

    // ---- Stage padded reversed H1/H2 tables (coalesced x reads) ----
    for (int i = tid; i < BN * DD; i += BLOCK) {
        int r = i / DD, c = i - r * DD;
        float xv = (x[(size_t)(row0 + r) * DD + c] - mean[c]) / var[c];
        float x2 = xv * xv;
        int k  = (DD - 1) - c;                         // reversed dim index
        int pk = k + (k >> 3);                         // pad: breaks stride-4
        T[r][pk]         = b10 + b11 * xv + b12 * x2;  // H1
        T[r][H2OFF + pk] = b20 + b21 * xv + b22 * x2;  // H2
    }
    if (tid < BN) T[tid][ONE] = 1.0f;                  // identity factor
    __syncthreads();

    // ---- Emit: 8 row-pairs, aligned float4 stores (1024 B/wave-instr) ----
    #pragma unroll
    for (int m = 0; m < NM; ++m) {
        const float* base = &T[2 * m][0];              // rows 2m,2m+1 adjacent
        float4* ob = (float4*)(out + (size_t)(row0 + 2 * m) * NBASIS); // 16B-al
        {
            int d0 = dsc[0][0], d1 = dsc[0][1], d2 = dsc[0][2], d3 = dsc[0][3];
            float4 w;
            w.x = base[d0 & 0xff] * base[d0 >> 8];
            w.y = base[d1 & 0xff] * base[d1 >> 8];
            w.z = base[d2 & 0xff] * base[d2 >> 8];
            w.w = base[d3 & 0xff] * base[d3 >> 8];
            ob[tid] = w;
        }
        {
            int d0 = dsc[1][0], d1 = dsc[1][1], d2 = dsc[1][2], d3 = dsc[1][3];
            float4 w;
            w.x = base[d0 & 0xff] * base[d0 >> 8];
            w.y = base[d1 & 0xff] * base[d1 >> 8];
            w.z = base[d2 & 0xff] * base[d2 >> 8];
            w.w = base[d3 & 0xff] * base[d3 >> 8];
            ob[tid + BLOCK] = w;
        }
        if (has2) {
            int d0 = dsc[2][0], d1 = dsc[2][1], d2 = dsc[2][2], d3 = dsc[2][3];
            float4 w;
            w.x = base[d0 & 0xff] * base[d0 >> 8];
            w.y = base[d1 & 0xff] * base[d1 >> 8];
            w.z = base[d2 & 0xff] * base[d2 >> 8];
            w.w = base[d3 & 0xff] * base[d3 >> 8];
            ob[tid + 2 * BLOCK] = w;
        }
    }
}

extern "C" void kernel_launch(void* const* d_in, const int* in_sizes, int n_in,
                              void* d_out, int out_size, void* d_ws, size_t ws_size,
                              hipStream_t stream) {
    const float* x     = (const float*)d_in[0];
    const float* mean  = (const float*)d_in[1];
    const float* var   = (const float*)d_in[2];
    const float* basis = (const float*)d_in[3];
    float* out = (float*)d_out;

    const int d = in_sizes[1];          // 50
    const int n = in_sizes[0] / d;      // 32768

    (void)d_ws; (void)ws_size;          // workspace intentionally unused

    pce_kernel<<<(n + BN - 1) / BN, BLOCK, 0, stream>>>(x, mean, var, basis, out, n);
}